// Round 11
// baseline (76.554 us; speedup 1.0000x reference)
//
#include <hip/hip_runtime.h>

typedef float floatx2 __attribute__((ext_vector_type(2)));
typedef float floatx4 __attribute__((ext_vector_type(4)));

constexpr int BLOCK = 256;   // 4 waves
constexpr int GRID  = 1024;  // 4 blocks/CU, all resident -> one dense moving write front

static __device__ __forceinline__ floatx2 fma2(floatx2 a, floatx2 b, floatx2 c) {
    return __builtin_elementwise_fma(a, b, c);   // -> v_pk_fma_f32 (verified round 7)
}

// ---- pre-kernel: Etab[b] = skew(t_b) @ R_b, 12 floats (3 x float4) per model ----
__global__ void build_E_kernel(const float* __restrict__ models,
                               float* __restrict__ Etab, int B)
{
    const int b = blockIdx.x * blockDim.x + threadIdx.x;
    if (b >= B) return;
    const float* m = models + (size_t)b * 12;
    const float t0 = m[3], t1 = m[7], t2 = m[11];
    float* e = Etab + b * 12;
    #pragma unroll
    for (int j = 0; j < 3; ++j) {
        const float R0 = m[0 + j], R1 = m[4 + j], R2 = m[8 + j];
        e[0 + j] = fmaf(-t2, R1,  t1 * R2);
        e[3 + j] = fmaf( t2, R0, -t0 * R2);
        e[6 + j] = fmaf(-t1, R0,  t0 * R1);
    }
    e[9] = e[10] = e[11] = 0.0f;
}

__global__ __launch_bounds__(BLOCK) void essential_dense_kernel(
    const float4* __restrict__ Etab,   // B x 3 float4 (E row-major, 3 pad floats)
    const float4* __restrict__ pts,    // N x (x1,y1,x2,y2)
    const float*  __restrict__ K1,
    const float*  __restrict__ K2,
    float*        __restrict__ out,    // flat B*N
    int N, unsigned total, unsigned long long nmagic)
{
    const float f1 = (K1[0] + K1[4]) * 0.5f;
    const float f2 = (K2[0] + K2[4]) * 0.5f;
    const float thr  = (1.0f / f1 + 1.0f / f2) * 0.5f;
    const float thr2 = thr * thr;
    const floatx2 thr2v = { thr2,  thr2 };
    const floatx2 onev  = { 1.0f,  1.0f };
    const floatx2 nonev = { -1.0f, -1.0f };
    const floatx2 zerov = { 0.0f,  0.0f };

    const unsigned stride = (unsigned)GRID * BLOCK * 4;
    for (unsigned i0 = (blockIdx.x * BLOCK + threadIdx.x) * 4; i0 < total; i0 += stride) {
        const unsigned b  = (unsigned)(((unsigned long long)i0 * nmagic) >> 48);
        const unsigned n0 = i0 - b * (unsigned)N;

        floatx4 v4;
        if (n0 <= (unsigned)(N - 4)) {
            // ---- fast path: all 4 outputs in row b, points n0..n0+3 ----
            const float4 e0 = Etab[b * 3 + 0];   // E0 E1 E2 E3
            const float4 e1 = Etab[b * 3 + 1];   // E4 E5 E6 E7
            const float4 e2 = Etab[b * 3 + 2];   // E8 -  -  -
            const floatx2 E0 = {e0.x,e0.x}, E1 = {e0.y,e0.y}, E2 = {e0.z,e0.z};
            const floatx2 E3 = {e0.w,e0.w}, E4 = {e1.x,e1.x}, E5 = {e1.y,e1.y};
            const floatx2 E6 = {e1.z,e1.z}, E7 = {e1.w,e1.w}, E8 = {e2.x,e2.x};

            float4 p[4];
            #pragma unroll
            for (int k = 0; k < 4; ++k) p[k] = pts[n0 + k];

            floatx2 rr[2];
            #pragma unroll
            for (int g = 0; g < 2; ++g) {
                const floatx2 px = { p[2*g].x, p[2*g+1].x };
                const floatx2 py = { p[2*g].y, p[2*g+1].y };
                const floatx2 pu = { p[2*g].z, p[2*g+1].z };
                const floatx2 pv = { p[2*g].w, p[2*g+1].w };

                const floatx2 a0 = fma2(E0, px, fma2(E1, py, E2));
                const floatx2 a1 = fma2(E3, px, fma2(E4, py, E5));
                const floatx2 b0 = fma2(E0, pu, fma2(E3, pv, E6));
                const floatx2 b1 = fma2(E1, pu, fma2(E4, pv, E7));
                const floatx2 b2 = fma2(E2, pu, fma2(E5, pv, E8));

                const floatx2 jj  = fma2(a0, a0, fma2(a1, a1, fma2(b0, b0, b1 * b1)));
                const floatx2 sv  = fma2(px, b0, fma2(py, b1, b2));
                const floatx2 num = sv * sv;
                const floatx2 jjt = jj * thr2v;
                const floatx2 rj  = { __builtin_amdgcn_rcpf(jjt.x),
                                      __builtin_amdgcn_rcpf(jjt.y) };
                const floatx2 d   = num * rj;
                const floatx2 r   = fma2(d, nonev, onev);     // 1 - d
                rr[g] = __builtin_elementwise_max(r, zerov);
            }
            v4 = floatx4{ rr[0].x, rr[0].y, rr[1].x, rr[1].y };
        } else {
            // ---- straddle path (row boundary inside chunk): per element, scalar ----
            float rs[4];
            #pragma unroll
            for (int k = 0; k < 4; ++k) {
                const unsigned i  = i0 + k;
                const unsigned bb = (unsigned)(((unsigned long long)i * nmagic) >> 48);
                const unsigned nn = i - bb * (unsigned)N;
                const float4 e0 = Etab[bb * 3 + 0];
                const float4 e1 = Etab[bb * 3 + 1];
                const float4 e2 = Etab[bb * 3 + 2];
                const float4 P  = pts[nn];
                const float x = P.x, y = P.y, u = P.z, v = P.w;
                const float a0 = fmaf(e0.x, x, fmaf(e0.y, y, e0.z));
                const float a1 = fmaf(e0.w, x, fmaf(e1.x, y, e1.y));
                const float b0 = fmaf(e0.x, u, fmaf(e0.w, v, e1.z));
                const float b1 = fmaf(e0.y, u, fmaf(e1.x, v, e1.w));
                const float b2 = fmaf(e0.z, u, fmaf(e1.y, v, e2.x));
                const float jj = fmaf(a0, a0, fmaf(a1, a1, fmaf(b0, b0, b1 * b1)));
                const float s  = fmaf(x, b0, fmaf(y, b1, b2));
                const float d  = (s * s) * __builtin_amdgcn_rcpf(jj * thr2);
                rs[k] = fmaxf(1.0f - d, 0.0f);
            }
            v4 = floatx4{ rs[0], rs[1], rs[2], rs[3] };
        }

        *reinterpret_cast<floatx4*>(out + i0) = v4;   // 16B store, dense front
    }
}

extern "C" void kernel_launch(void* const* d_in, const int* in_sizes, int n_in,
                              void* d_out, int out_size, void* d_ws, size_t ws_size,
                              hipStream_t stream)
{
    const float* models = (const float*)d_in[0];
    const float* points = (const float*)d_in[1];
    const float* K1     = (const float*)d_in[2];
    const float* K2     = (const float*)d_in[3];
    float* out  = (float*)d_out;
    float* Etab = (float*)d_ws;               // B*12 floats = 24 KB

    const int B = in_sizes[0] / 12;           // 512
    const int N = in_sizes[1] / 4;            // 100000
    const unsigned total = (unsigned)B * (unsigned)N;
    const unsigned long long nmagic = ((1ULL << 48) + (unsigned)N - 1) / (unsigned)N;

    build_E_kernel<<<(B + 255) / 256, 256, 0, stream>>>(models, Etab, B);
    essential_dense_kernel<<<GRID, BLOCK, 0, stream>>>(
        (const float4*)Etab, (const float4*)points, K1, K2, out, N, total, nmagic);
}

// Round 12
// 40.131 us; speedup vs baseline: 1.9076x; 1.9076x over previous
//
#include <hip/hip_runtime.h>

typedef float floatx2 __attribute__((ext_vector_type(2)));
typedef float floatx4 __attribute__((ext_vector_type(4)));

constexpr int BLOCK = 256;
constexpr int PPT   = 4;    // 16B/lane coalesced stores
constexpr int MPB   = 32;   // point fetch amortized 32x
constexpr int NXCD  = 8;

static __device__ __forceinline__ floatx2 fma2(floatx2 a, floatx2 b, floatx2 c) {
    return __builtin_elementwise_fma(a, b, c);   // -> v_pk_fma_f32 (verified round 7)
}

__global__ __launch_bounds__(BLOCK) void essential_msac_kernel(
    const float*  __restrict__ models,  // B x 3 x 4
    const float4* __restrict__ pts,     // N x (x1,y1,x2,y2)
    const float*  __restrict__ K1,      // 3x3
    const float*  __restrict__ K2,      // 3x3
    float*        __restrict__ out,     // B x N
    int B, int N)
{
    // ---- XCD-aware bijective swizzle (T1). grid.x*grid.y must be % 8 == 0. ----
    // Dispatch-order flat id round-robins over 8 XCDs; remap so each XCD owns a
    // contiguous chunk of column-tiles across ALL model bands: point columns are
    // fetched into ONE XCD L2, and each XCD's writeback window is contiguous.
    const unsigned nwg   = gridDim.x * gridDim.y;
    const unsigned f     = blockIdx.y * gridDim.x + blockIdx.x;   // dispatch order
    const unsigned chunk = nwg / NXCD;
    const unsigned f2    = (f & (NXCD - 1)) * chunk + (f >> 3);
    const unsigned bx    = f2 / gridDim.y;    // column tile 0..97
    const unsigned by    = f2 % gridDim.y;    // model band 0..15

    __shared__ float Es[MPB][9];

    const int bm0  = by * MPB;
    const int mEnd = min(MPB, B - bm0);

    if ((int)threadIdx.x < mEnd) {
        const float* m = models + (size_t)(bm0 + threadIdx.x) * 12;
        const float t0 = m[3], t1 = m[7], t2 = m[11];
        #pragma unroll
        for (int j = 0; j < 3; ++j) {
            const float R0 = m[0 + j], R1 = m[4 + j], R2 = m[8 + j];
            Es[threadIdx.x][0 + j] = fmaf(-t2, R1,  t1 * R2);
            Es[threadIdx.x][3 + j] = fmaf( t2, R0, -t0 * R2);
            Es[threadIdx.x][6 + j] = fmaf(-t1, R0,  t0 * R1);
        }
    }
    __syncthreads();

    const float f1 = (K1[0] + K1[4]) * 0.5f;
    const float f2k = (K2[0] + K2[4]) * 0.5f;
    const float thr  = (1.0f / f1 + 1.0f / f2k) * 0.5f;
    const float thr2 = thr * thr;
    const floatx2 thr2v = { thr2,  thr2 };
    const floatx2 onev  = { 1.0f,  1.0f };
    const floatx2 nonev = { -1.0f, -1.0f };
    const floatx2 zerov = { 0.0f,  0.0f };

    const int n0 = (bx * BLOCK + threadIdx.x) * PPT;
    if (n0 >= N) return;   // N % 4 == 0

    float4 p[PPT];
    #pragma unroll
    for (int k = 0; k < PPT; ++k) p[k] = pts[n0 + k];

    floatx2 px[2], py[2], pu[2], pv[2];
    #pragma unroll
    for (int g = 0; g < 2; ++g) {
        px[g] = { p[2*g].x, p[2*g+1].x };
        py[g] = { p[2*g].y, p[2*g+1].y };
        pu[g] = { p[2*g].z, p[2*g+1].z };
        pv[g] = { p[2*g].w, p[2*g+1].w };
    }

    auto comp = [&](const float* e) -> floatx4 {
        const floatx2 E0 = {e[0],e[0]}, E1 = {e[1],e[1]}, E2 = {e[2],e[2]};
        const floatx2 E3 = {e[3],e[3]}, E4 = {e[4],e[4]}, E5 = {e[5],e[5]};
        const floatx2 E6 = {e[6],e[6]}, E7 = {e[7],e[7]}, E8 = {e[8],e[8]};
        floatx2 rr[2];
        #pragma unroll
        for (int g = 0; g < 2; ++g) {
            const floatx2 a0 = fma2(E0, px[g], fma2(E1, py[g], E2));
            const floatx2 a1 = fma2(E3, px[g], fma2(E4, py[g], E5));
            const floatx2 b0 = fma2(E0, pu[g], fma2(E3, pv[g], E6));
            const floatx2 b1 = fma2(E1, pu[g], fma2(E4, pv[g], E7));
            const floatx2 b2 = fma2(E2, pu[g], fma2(E5, pv[g], E8));

            const floatx2 jj  = fma2(a0, a0, fma2(a1, a1, fma2(b0, b0, b1 * b1)));
            const floatx2 s   = fma2(px[g], b0, fma2(py[g], b1, b2));
            const floatx2 num = s * s;
            const floatx2 jjt = jj * thr2v;
            const floatx2 rj  = { __builtin_amdgcn_rcpf(jjt.x),
                                  __builtin_amdgcn_rcpf(jjt.y) };
            const floatx2 d   = num * rj;
            const floatx2 r   = fma2(d, nonev, onev);     // 1 - d
            rr[g] = __builtin_elementwise_max(r, zerov);
        }
        return floatx4{ rr[0].x, rr[0].y, rr[1].x, rr[1].y };
    };

    float* o = out + (size_t)bm0 * N + n0;
    int mi = 0;
    for (; mi + 2 <= mEnd; mi += 2) {
        const floatx4 va = comp(Es[mi]);
        const floatx4 vb = comp(Es[mi + 1]);
        *reinterpret_cast<floatx4*>(o)     = va;
        *reinterpret_cast<floatx4*>(o + N) = vb;
        o += 2 * (size_t)N;
    }
    if (mi < mEnd) {
        const floatx4 va = comp(Es[mi]);
        *reinterpret_cast<floatx4*>(o) = va;
    }
}

extern "C" void kernel_launch(void* const* d_in, const int* in_sizes, int n_in,
                              void* d_out, int out_size, void* d_ws, size_t ws_size,
                              hipStream_t stream)
{
    const float* models = (const float*)d_in[0];
    const float* points = (const float*)d_in[1];
    const float* K1     = (const float*)d_in[2];
    const float* K2     = (const float*)d_in[3];
    float* out = (float*)d_out;

    const int B = in_sizes[0] / 12;   // 512
    const int N = in_sizes[1] / 4;    // 100000

    dim3 grid((N + BLOCK * PPT - 1) / (BLOCK * PPT),   // 98
              (B + MPB - 1) / MPB);                    // 16  -> 1568 blocks, %8==0
    essential_msac_kernel<<<grid, BLOCK, 0, stream>>>(
        models, (const float4*)points, K1, K2, out, B, N);
}